// Round 13
// baseline (129.057 us; speedup 1.0000x reference)
//
#include <hip/hip_runtime.h>

#define NB 4
#define NC 256
#define NCK 32
#define NPIX 4096
#define TOT (NB * NC * NPIX)

typedef unsigned short u16;
typedef unsigned int u32;
typedef __bf16 bfv8 __attribute__((ext_vector_type(8)));
typedef float f32x4 __attribute__((ext_vector_type(4)));
#define LOG2E 1.4426950408889634f

__device__ inline u16 f2bf(float f) {
  union { float f; u32 u; } v; v.f = f;
  u32 r = v.u + 0x7fffu + ((v.u >> 16) & 1u);  // RNE
  return (u16)(r >> 16);
}
__device__ inline float bf2f(u16 h) {
  union { u32 u; float f; } v; v.u = (u32)h << 16; return v.f;
}
__device__ inline u32 cvtpk(float a, float b) {
  u32 r;
  asm("v_cvt_pk_bf16_f32 %0, %1, %2" : "=v"(r) : "v"(a), "v"(b));
  return r;
}

// ---------------- K3: f,g projections + xT emit ----------------
__global__ __launch_bounds__(256) void k_fg(const float* __restrict__ x,
                                            const float* __restrict__ Wf,
                                            const float* __restrict__ bf_,
                                            const float* __restrict__ Wg,
                                            const float* __restrict__ bg_,
                                            u16* __restrict__ fP,
                                            u16* __restrict__ gT,
                                            u16* __restrict__ xT) {
  __shared__ float Wt[256][65];
  __shared__ float xl[32][68];
  __shared__ float tb[64][68];
  int blk = blockIdx.x;
  int b = blk >> 6;
  int n0 = (blk & 63) * 64;
  int t = threadIdx.x;
  int tx = t & 15, ty = t >> 4;
  for (int r = 0; r < 64; r++) {
    float w = (r < 32) ? Wf[r * 256 + t] : Wg[(r - 32) * 256 + t];
    Wt[t][r] = w;
  }
  float acc[4][4] = {};
  int n = t >> 2, cp = t & 3;
  for (int kc = 0; kc < 8; kc++) {
    __syncthreads();
#pragma unroll
    for (int r = 0; r < 2; r++) {
      int e = (r * 256 + t) * 4;
      int row = e >> 6, col = e & 63;
      *(float4*)&xl[row][col] =
          *(const float4*)(x + ((size_t)(b * NC + kc * 32 + row)) * NPIX + n0 + col);
    }
    __syncthreads();
    {
      u32 uu[4];
#pragma unroll
      for (int q = 0; q < 4; q++)
        uu[q] = cvtpk(xl[cp * 8 + 2 * q][n], xl[cp * 8 + 2 * q + 1][n]);
      *(uint4*)(xT + ((size_t)(b * NPIX) + n0 + n) * NC + kc * 32 + cp * 8) =
          make_uint4(uu[0], uu[1], uu[2], uu[3]);
    }
#pragma unroll
    for (int kk = 0; kk < 32; kk++) {
      float4 xv = *(const float4*)&xl[kk][tx * 4];
      float w0 = Wt[kc * 32 + kk][ty * 4 + 0];
      float w1 = Wt[kc * 32 + kk][ty * 4 + 1];
      float w2 = Wt[kc * 32 + kk][ty * 4 + 2];
      float w3 = Wt[kc * 32 + kk][ty * 4 + 3];
      acc[0][0] += w0 * xv.x; acc[0][1] += w0 * xv.y; acc[0][2] += w0 * xv.z; acc[0][3] += w0 * xv.w;
      acc[1][0] += w1 * xv.x; acc[1][1] += w1 * xv.y; acc[1][2] += w1 * xv.z; acc[1][3] += w1 * xv.w;
      acc[2][0] += w2 * xv.x; acc[2][1] += w2 * xv.y; acc[2][2] += w2 * xv.z; acc[2][3] += w2 * xv.w;
      acc[3][0] += w3 * xv.x; acc[3][1] += w3 * xv.y; acc[3][2] += w3 * xv.z; acc[3][3] += w3 * xv.w;
    }
  }
#pragma unroll
  for (int j = 0; j < 4; j++) {
    int o = ty * 4 + j;
    float bias = (o < 32) ? bf_[o] : bg_[o - 32];
#pragma unroll
    for (int vi = 0; vi < 4; vi++) tb[tx * 4 + vi][o] = acc[j][vi] + bias;
  }
  __syncthreads();
  int part = t & 3;
  {
    u32 ph[4], plo[4];
#pragma unroll
    for (int e = 0; e < 4; e++) {
      float v0 = tb[n][part * 8 + 2 * e + 0];
      float v1 = tb[n][part * 8 + 2 * e + 1];
      u16 h0 = f2bf(v0), h1 = f2bf(v1);
      u16 l0 = f2bf(v0 - bf2f(h0)), l1 = f2bf(v1 - bf2f(h1));
      ph[e] = (u32)h0 | ((u32)h1 << 16);
      plo[e] = (u32)l0 | ((u32)l1 << 16);
    }
    int jt_g = (n0 >> 4) + (n >> 4), r = n & 15;
    u16* dst = fP + ((size_t)(b * 256) + jt_g) * 1024 + r * 32 + part * 8;
    *(uint4*)dst = make_uint4(ph[0], ph[1], ph[2], ph[3]);
    *(uint4*)(dst + 512) = make_uint4(plo[0], plo[1], plo[2], plo[3]);
  }
  {
    u32 ph[4], plo[4];
#pragma unroll
    for (int e = 0; e < 4; e++) {
      float v0 = tb[n][32 + part * 8 + 2 * e + 0];
      float v1 = tb[n][32 + part * 8 + 2 * e + 1];
      u16 h0 = f2bf(v0), h1 = f2bf(v1);
      u16 l0 = f2bf(v0 - bf2f(h0)), l1 = f2bf(v1 - bf2f(h1));
      ph[e] = (u32)h0 | ((u32)h1 << 16);
      plo[e] = (u32)l0 | ((u32)l1 << 16);
    }
    u16* dst = gT + ((size_t)(b * NPIX) + n0 + n) * 64 + part * 8;
    *(uint4*)dst = make_uint4(ph[0], ph[1], ph[2], ph[3]);
    *(uint4*)(dst + 32) = make_uint4(plo[0], plo[1], plo[2], plo[3]);
  }
}

// ---------------- K4: h projection -> h2[b][j>>5][c][j&31] bf16 ----------------
__global__ __launch_bounds__(256) void k_h(const u16* __restrict__ xT,
                                           const float* __restrict__ Wh,
                                           const float* __restrict__ bh,
                                           u16* __restrict__ h2) {
  __shared__ u16 At[128 * 32];
  __shared__ u16 Bt[128 * 32];
  int blk = blockIdx.x;
  int b = blk >> 6, r = blk & 63;
  int nt = r >> 1, ot = r & 1;
  int n0 = nt * 128, o0 = ot * 128;
  int t = threadIdx.x, lane = t & 63, w = t >> 6;
  int wr = w >> 1, wc = w & 1;
  int coll = lane & 15, cg = lane >> 4;
  f32x4 acc[4][4] = {};
  for (int kc = 0; kc < 8; kc++) {
    __syncthreads();
#pragma unroll
    for (int r2 = 0; r2 < 2; r2++) {
      int s = r2 * 256 + t;
      int row = s >> 2, slot = s & 3;
      int sw = (row ^ (row >> 2)) & 3;
      uint4 va = *(const uint4*)(xT + ((size_t)(b * NPIX + n0 + row)) * NC + kc * 32 + slot * 8);
      *(uint4*)((char*)At + row * 64 + ((slot ^ sw) * 16)) = va;
      const float* wsrc = Wh + (size_t)(o0 + row) * NC + kc * 32 + slot * 8;
      float4 w0 = *(const float4*)wsrc;
      float4 w1 = *(const float4*)(wsrc + 4);
      uint4 vb = make_uint4(cvtpk(w0.x, w0.y), cvtpk(w0.z, w0.w),
                            cvtpk(w1.x, w1.y), cvtpk(w1.z, w1.w));
      *(uint4*)((char*)Bt + row * 64 + ((slot ^ sw) * 16)) = vb;
    }
    __syncthreads();
    bfv8 af[4], bfr[4];
#pragma unroll
    for (int mi = 0; mi < 4; mi++) {
      int row = wr * 64 + mi * 16 + coll;
      int slot = cg ^ ((row ^ (row >> 2)) & 3);
      af[mi] = *(const bfv8*)((const char*)At + row * 64 + slot * 16);
    }
#pragma unroll
    for (int ni = 0; ni < 4; ni++) {
      int row = wc * 64 + ni * 16 + coll;
      int slot = cg ^ ((row ^ (row >> 2)) & 3);
      bfr[ni] = *(const bfv8*)((const char*)Bt + row * 64 + slot * 16);
    }
#pragma unroll
    for (int mi = 0; mi < 4; mi++)
#pragma unroll
      for (int ni = 0; ni < 4; ni++)
        acc[mi][ni] = __builtin_amdgcn_mfma_f32_16x16x32_bf16(af[mi], bfr[ni], acc[mi][ni], 0, 0, 0);
  }
#pragma unroll
  for (int ni = 0; ni < 4; ni++) {
    int o = o0 + wc * 64 + ni * 16 + coll;
    float bias = bh[o];
#pragma unroll
    for (int mi = 0; mi < 4; mi++) {
      int px = n0 + wr * 64 + mi * 16 + cg * 4;
      u32 lo = cvtpk(acc[mi][ni][0] + bias, acc[mi][ni][1] + bias);
      u32 hi = cvtpk(acc[mi][ni][2] + bias, acc[mi][ni][3] + bias);
      *(uint2*)(h2 + (((size_t)(b * 128) + (px >> 5)) * NC + o) * 32 + (px & 31)) =
          make_uint2(lo, hi);
    }
  }
}

// ---------------- K5: pass 1 partials ----------------
__global__ __launch_bounds__(256) void k_pass1(const u16* __restrict__ fP,
                                               const u16* __restrict__ gT,
                                               float2* __restrict__ pmd) {
  __shared__ u16 gs[64 * 64];
  int blk = blockIdx.x;
  int iq = blk & 7, jt = (blk >> 3) & 63, b = blk >> 9;
  int j0 = jt * 64, ibase = iq * 512;
  int t = threadIdx.x, lane = t & 63, w = t >> 6;
  int coll = lane & 15, cg = lane >> 4;
  const u16* fr = fP + ((size_t)(b * 256) + (j0 >> 4) + w) * 1024 + coll * 32 + cg * 8;
  bfv8 ah = *(const bfv8*)fr;
  bfv8 al = *(const bfv8*)(fr + 512);
  float m[4] = {-3e38f, -3e38f, -3e38f, -3e38f}, d[4] = {0.f, 0.f, 0.f, 0.f};
  int r0 = t >> 3, s0 = t & 7;
  uint4 v0 = *(const uint4*)(gT + ((size_t)(b * NPIX) + ibase + r0) * 64 + s0 * 8);
  uint4 v1 = *(const uint4*)(gT + ((size_t)(b * NPIX) + ibase + 32 + r0) * 64 + s0 * 8);
  for (int it2 = 0; it2 < 8; ++it2) {
    __syncthreads();
    *(uint4*)(&gs[r0 * 64 + ((s0 ^ (r0 & 7)) << 3)]) = v0;
    *(uint4*)(&gs[(32 + r0) * 64 + ((s0 ^ (r0 & 7)) << 3)]) = v1;
    __syncthreads();
    if (it2 < 7) {
      v0 = *(const uint4*)(gT + ((size_t)(b * NPIX) + ibase + (it2 + 1) * 64 + r0) * 64 + s0 * 8);
      v1 = *(const uint4*)(gT + ((size_t)(b * NPIX) + ibase + (it2 + 1) * 64 + 32 + r0) * 64 + s0 * 8);
    }
    float sv[4][4];
#pragma unroll
    for (int t4 = 0; t4 < 4; ++t4) {
      int row = t4 * 16 + coll;
      const u16* base = &gs[row * 64];
      bfv8 bh = *(const bfv8*)(base + ((cg ^ (row & 7)) << 3));
      bfv8 bl = *(const bfv8*)(base + (((4 + cg) ^ (row & 7)) << 3));
      f32x4 s = {0.f, 0.f, 0.f, 0.f};
      s = __builtin_amdgcn_mfma_f32_16x16x32_bf16(al, bh, s, 0, 0, 0);
      s = __builtin_amdgcn_mfma_f32_16x16x32_bf16(ah, bl, s, 0, 0, 0);
      s = __builtin_amdgcn_mfma_f32_16x16x32_bf16(ah, bh, s, 0, 0, 0);
      sv[t4][0] = s[0]; sv[t4][1] = s[1]; sv[t4][2] = s[2]; sv[t4][3] = s[3];
    }
#pragma unroll
    for (int r = 0; r < 4; ++r) {
      float ms = fmaxf(fmaxf(sv[0][r], sv[1][r]), fmaxf(sv[2][r], sv[3][r]));
      float nm = fmaxf(m[r], ms);
      d[r] = d[r] * __expf(m[r] - nm) + __expf(sv[0][r] - nm) + __expf(sv[1][r] - nm) +
             __expf(sv[2][r] - nm) + __expf(sv[3][r] - nm);
      m[r] = nm;
    }
  }
#pragma unroll
  for (int r = 0; r < 4; ++r) {
#pragma unroll
    for (int off = 1; off < 16; off <<= 1) {
      float m2 = __shfl_xor(m[r], off);
      float d2 = __shfl_xor(d[r], off);
      float nm = fmaxf(m[r], m2);
      d[r] = d[r] * __expf(m[r] - nm) + d2 * __expf(m2 - nm);
      m[r] = nm;
    }
  }
  if (coll == 0) {
#pragma unroll
    for (int r = 0; r < 4; ++r) {
      int j = j0 + w * 16 + cg * 4 + r;
      pmd[((size_t)(b * 8 + iq)) * NPIX + j] = make_float2(m[r], d[r]);
    }
  }
}

// ---------------- K5b: combine partials -> a_j = M*log2e + log2(D) ----------------
__global__ __launch_bounds__(256) void k_comb(const float2* __restrict__ pmd,
                                              float* __restrict__ aout) {
  int idx = blockIdx.x * 256 + threadIdx.x;  // 16384
  int b = idx >> 12, j = idx & 4095;
  float2 p[8];
  float M = -3e38f;
#pragma unroll
  for (int q = 0; q < 8; ++q) {
    p[q] = pmd[((size_t)(b * 8 + q)) * NPIX + j];
    M = fmaxf(M, p[q].x);
  }
  float D = 0.f;
#pragma unroll
  for (int q = 0; q < 8; ++q) D += p[q].y * __expf(p[q].x - M);
  aout[idx] = fmaf(M, LOG2E, __log2f(D));
}

// ---------------- K6: pass 2 — i-tile 128, 512 thr, jsplit 4 (2 blocks/CU) ----------------
// QK: wave (jt_w = w&3, ghalf = w>>2) computes S-tiles (jt_w, isub = ghalf*4+q), g resident.
// PV: wave owns c-slice [w*32, w*32+32) x i 128.
__global__ __launch_bounds__(512, 2) void k_pass2(const u16* __restrict__ fP,
                                                  const u16* __restrict__ gT,
                                                  const u16* __restrict__ h2,
                                                  const float* __restrict__ arow,
                                                  u16* __restrict__ Opart) {
  // pl: 2 phases x [8 isub][16 i][64 j] bf16 = 32KB at [0,32768); alds 2x64 f32 at 32768
  // epilogue alias: per-wave 16x68 f32 at w*4352 (34816 total)
  __shared__ char smem[34816];
  int blk = blockIdx.x;
  int jq = blk & 3, it = (blk >> 2) & 31, b = blk >> 7;
  int i0 = it * 128, jbase = jq * 1024;
  int t = threadIdx.x, lane = t & 63, w = t >> 6;
  int coll = lane & 15, cg = lane >> 4;
  int jt_w = w & 3, ghalf = w >> 2;
  int cbase = w * 32;
  int swz = (coll & 7) << 4;
  float* alds = (float*)(smem + 32768);
  // g B-frags: 4 isub tiles, resident for the whole kernel
  bfv8 gah[4], gal[4];
#pragma unroll
  for (int q = 0; q < 4; ++q) {
    const u16* gr = gT + ((size_t)(b * NPIX) + i0 + (ghalf * 4 + q) * 16 + coll) * 64 + cg * 8;
    gah[q] = *(const bfv8*)gr;
    gal[q] = *(const bfv8*)(gr + 32);
  }
  f32x4 acc[2][8] = {};  // [ct (c 16-sub)][ni (i 16-sub of 128)]
  // h A-frags: c-slice 32 x j-chunk 64, contiguous 1024B wave loads
  const u16* h2b = h2 + (((size_t)(b * 128) + (jbase >> 5)) * NC + cbase + coll) * 32 + cg * 8;
  bfv8 hv[2][2];
#pragma unroll
  for (int ct = 0; ct < 2; ++ct)
#pragma unroll
    for (int kb = 0; kb < 2; ++kb)
      hv[ct][kb] = *(const bfv8*)(h2b + (size_t)kb * 8192 + ct * 512);
  // f A-frags: this wave's single j-subtile per chunk
  const u16* fPb = fP + ((size_t)(b * 256) + (jbase >> 4)) * 1024 + coll * 32 + cg * 8;
  bfv8 fh = *(const bfv8*)(fPb + jt_w * 1024);
  bfv8 fl = *(const bfv8*)(fPb + jt_w * 1024 + 512);
  float apre = 0.f;
  if (t < 64) alds[t] = arow[b * NPIX + jbase + t];
  // QK(0): 4 S-tiles
  f32x4 s[4];
#pragma unroll
  for (int q = 0; q < 4; ++q) {
    f32x4 ss = {0.f, 0.f, 0.f, 0.f};
    ss = __builtin_amdgcn_mfma_f32_16x16x32_bf16(fl, gah[q], ss, 0, 0, 0);
    ss = __builtin_amdgcn_mfma_f32_16x16x32_bf16(fh, gal[q], ss, 0, 0, 0);
    ss = __builtin_amdgcn_mfma_f32_16x16x32_bf16(fh, gah[q], ss, 0, 0, 0);
    s[q] = ss;
  }
  // f(1), a(1)
  fh = *(const bfv8*)(fPb + (4 + jt_w) * 1024);
  fl = *(const bfv8*)(fPb + (4 + jt_w) * 1024 + 512);
  if (t < 64) apre = arow[b * NPIX + jbase + 64 + t];
  __syncthreads();

  for (int jc = 0; jc < 16; ++jc) {
    int p = jc & 1;
    // ---- exp + P write (4 tiles share the same j-rows -> one av) ----
    {
      int jr = jt_w * 16 + cg * 4;
      float4 av = *(const float4*)&alds[p * 64 + jr];
#pragma unroll
      for (int q = 0; q < 4; ++q) {
        float p0 = exp2f(fmaf(s[q][0], LOG2E, -av.x));
        float p1 = exp2f(fmaf(s[q][1], LOG2E, -av.y));
        float p2 = exp2f(fmaf(s[q][2], LOG2E, -av.z));
        float p3 = exp2f(fmaf(s[q][3], LOG2E, -av.w));
        char* pb = smem + p * 16384 + (ghalf * 4 + q) * 2048 + coll * 128;
        *(uint2*)(pb + ((jt_w * 32 + cg * 8) ^ swz)) =
            make_uint2(cvtpk(p0, p1), cvtpk(p2, p3));
      }
    }
    if (t < 64) alds[((jc + 1) & 1) * 64 + t] = apre;
    __syncthreads();
    // ---- PV: c-slice 32 x i 128 ----
#pragma unroll
    for (int ni = 0; ni < 8; ++ni) {
      const char* pbr = smem + p * 16384 + ni * 2048 + coll * 128;
      bfv8 pa0 = *(const bfv8*)(pbr + ((cg * 16) ^ swz));
      bfv8 pa1 = *(const bfv8*)(pbr + ((64 + cg * 16) ^ swz));
#pragma unroll
      for (int ct = 0; ct < 2; ++ct) {
        acc[ct][ni] = __builtin_amdgcn_mfma_f32_16x16x32_bf16(hv[ct][0], pa0, acc[ct][ni], 0, 0, 0);
        acc[ct][ni] = __builtin_amdgcn_mfma_f32_16x16x32_bf16(hv[ct][1], pa1, acc[ct][ni], 0, 0, 0);
      }
    }
    if (jc < 15) {
      // next h frags
#pragma unroll
      for (int ct = 0; ct < 2; ++ct)
#pragma unroll
        for (int kb = 0; kb < 2; ++kb)
          hv[ct][kb] = *(const bfv8*)(h2b + (size_t)((jc + 1) * 2 + kb) * 8192 + ct * 512);
      // QK(jc+1) with resident g
#pragma unroll
      for (int q = 0; q < 4; ++q) {
        f32x4 ss = {0.f, 0.f, 0.f, 0.f};
        ss = __builtin_amdgcn_mfma_f32_16x16x32_bf16(fl, gah[q], ss, 0, 0, 0);
        ss = __builtin_amdgcn_mfma_f32_16x16x32_bf16(fh, gal[q], ss, 0, 0, 0);
        ss = __builtin_amdgcn_mfma_f32_16x16x32_bf16(fh, gah[q], ss, 0, 0, 0);
        s[q] = ss;
      }
      if (jc < 14) {
        fh = *(const bfv8*)(fPb + (size_t)((jc + 2) * 4 + jt_w) * 1024);
        fl = *(const bfv8*)(fPb + (size_t)((jc + 2) * 4 + jt_w) * 1024 + 512);
        if (t < 64) apre = arow[b * NPIX + jbase + (jc + 2) * 64 + t];
      }
    }
  }
  // ---- epilogue: per-wave transpose via LDS, write bf16 partials ----
  int row = lane >> 2, part = lane & 3;
  __syncthreads();
#pragma unroll
  for (int ct = 0; ct < 2; ++ct) {
#pragma unroll
    for (int ih = 0; ih < 2; ++ih) {
      __syncthreads();
      float* tbf = (float*)(smem + w * 4352);
#pragma unroll
      for (int nq = 0; nq < 4; ++nq)
#pragma unroll
        for (int r = 0; r < 4; ++r)
          tbf[(cg * 4 + r) * 68 + nq * 16 + coll] = acc[ct][ih * 4 + nq][r];
      __syncthreads();
      const float* src = tbf + row * 68 + part * 16;
      u32 uu[8];
#pragma unroll
      for (int q = 0; q < 8; ++q) uu[q] = cvtpk(src[2 * q], src[2 * q + 1]);
      u16* op = Opart + (size_t)jq * TOT +
                ((size_t)(b * NC) + cbase + ct * 16 + row) * NPIX + i0 + ih * 64 + part * 16;
      *(uint4*)op = make_uint4(uu[0], uu[1], uu[2], uu[3]);
      *(uint4*)(op + 8) = make_uint4(uu[4], uu[5], uu[6], uu[7]);
    }
  }
}

// ---------------- K7: reduce 4 partials + residual ----------------
__global__ __launch_bounds__(256) void k_reduce(const u16* __restrict__ Opart,
                                                const float* __restrict__ x,
                                                const float* __restrict__ gamma,
                                                float* __restrict__ out) {
  int i = (blockIdx.x * 256 + threadIdx.x) * 4;
  float s0 = 0.f, s1 = 0.f, s2 = 0.f, s3 = 0.f;
#pragma unroll
  for (int q = 0; q < 4; ++q) {
    uint2 a = *(const uint2*)(Opart + (size_t)q * TOT + i);
    s0 += bf2f((u16)(a.x & 0xffff));
    s1 += bf2f((u16)(a.x >> 16));
    s2 += bf2f((u16)(a.y & 0xffff));
    s3 += bf2f((u16)(a.y >> 16));
  }
  float4 xv = *(const float4*)(x + i);
  float gam = gamma[0];
  float4 ov;
  ov.x = gam * s0 + xv.x;
  ov.y = gam * s1 + xv.y;
  ov.z = gam * s2 + xv.z;
  ov.w = gam * s3 + xv.w;
  *(float4*)(out + i) = ov;
}

extern "C" void kernel_launch(void* const* d_in, const int* in_sizes, int n_in,
                              void* d_out, int out_size, void* d_ws, size_t ws_size,
                              hipStream_t stream) {
  (void)in_sizes; (void)n_in; (void)out_size; (void)ws_size;
  const float* x = (const float*)d_in[0];
  const float* Wf = (const float*)d_in[1];
  const float* bf_ = (const float*)d_in[2];
  const float* Wg = (const float*)d_in[3];
  const float* bg_ = (const float*)d_in[4];
  const float* Wh = (const float*)d_in[5];
  const float* bh = (const float*)d_in[6];
  const float* gamma = (const float*)d_in[7];
  float* out = (float*)d_out;
  char* ws = (char*)d_ws;
  const size_t M1 = 1u << 20;
  // xT @0 (8MB, dead after k_h); Opart @0 (4 bf16 partials, 33.6MB);
  // h2 @34M (8MB); fP @42M (2MB); gT @44M (2MB); aout @46M; pmd @46M+128K. Total ~47.2MB
  // (ws_size >= 48MB verified empirically in round 9's jsplit=4 run.)
  u16* xT = (u16*)ws;
  u16* Opart = (u16*)ws;
  u16* h2 = (u16*)(ws + 34 * M1);
  u16* fP = (u16*)(ws + 42 * M1);
  u16* gT = (u16*)(ws + 44 * M1);
  float* aout = (float*)(ws + 46 * M1);
  float2* pmd = (float2*)(ws + 46 * M1 + (1u << 17));

  k_fg<<<256, 256, 0, stream>>>(x, Wf, bf_, Wg, bg_, fP, gT, xT);
  k_pass1<<<2048, 256, 0, stream>>>(fP, gT, pmd);
  k_h<<<256, 256, 0, stream>>>(xT, Wh, bh, h2);
  k_comb<<<64, 256, 0, stream>>>(pmd, aout);
  k_pass2<<<512, 512, 0, stream>>>(fP, gT, h2, aout, Opart);
  k_reduce<<<4096, 256, 0, stream>>>(Opart, x, gamma, out);
}

// Round 14
// 118.004 us; speedup vs baseline: 1.0937x; 1.0937x over previous
//
#include <hip/hip_runtime.h>

#define NB 4
#define NC 256
#define NCK 32
#define NPIX 4096

typedef unsigned short u16;
typedef unsigned int u32;
typedef __bf16 bfv8 __attribute__((ext_vector_type(8)));
typedef float f32x4 __attribute__((ext_vector_type(4)));
#define LOG2E 1.4426950408889634f

__device__ inline u16 f2bf(float f) {
  union { float f; u32 u; } v; v.f = f;
  u32 r = v.u + 0x7fffu + ((v.u >> 16) & 1u);  // RNE
  return (u16)(r >> 16);
}
__device__ inline float bf2f(u16 h) {
  union { u32 u; float f; } v; v.u = (u32)h << 16; return v.f;
}
__device__ inline u32 cvtpk(float a, float b) {
  u32 r;
  asm("v_cvt_pk_bf16_f32 %0, %1, %2" : "=v"(r) : "v"(a), "v"(b));
  return r;
}

// ---------------- K3: f,g projections + xT emit ----------------
__global__ __launch_bounds__(256) void k_fg(const float* __restrict__ x,
                                            const float* __restrict__ Wf,
                                            const float* __restrict__ bf_,
                                            const float* __restrict__ Wg,
                                            const float* __restrict__ bg_,
                                            u16* __restrict__ fP,
                                            u16* __restrict__ gT,
                                            u16* __restrict__ xT) {
  __shared__ float Wt[256][65];
  __shared__ float xl[32][68];
  __shared__ float tb[64][68];
  int blk = blockIdx.x;
  int b = blk >> 6;
  int n0 = (blk & 63) * 64;
  int t = threadIdx.x;
  int tx = t & 15, ty = t >> 4;
  for (int r = 0; r < 64; r++) {
    float w = (r < 32) ? Wf[r * 256 + t] : Wg[(r - 32) * 256 + t];
    Wt[t][r] = w;
  }
  float acc[4][4] = {};
  int n = t >> 2, cp = t & 3;
  for (int kc = 0; kc < 8; kc++) {
    __syncthreads();
#pragma unroll
    for (int r = 0; r < 2; r++) {
      int e = (r * 256 + t) * 4;
      int row = e >> 6, col = e & 63;
      *(float4*)&xl[row][col] =
          *(const float4*)(x + ((size_t)(b * NC + kc * 32 + row)) * NPIX + n0 + col);
    }
    __syncthreads();
    {
      u32 uu[4];
#pragma unroll
      for (int q = 0; q < 4; q++)
        uu[q] = cvtpk(xl[cp * 8 + 2 * q][n], xl[cp * 8 + 2 * q + 1][n]);
      *(uint4*)(xT + ((size_t)(b * NPIX) + n0 + n) * NC + kc * 32 + cp * 8) =
          make_uint4(uu[0], uu[1], uu[2], uu[3]);
    }
#pragma unroll
    for (int kk = 0; kk < 32; kk++) {
      float4 xv = *(const float4*)&xl[kk][tx * 4];
      float w0 = Wt[kc * 32 + kk][ty * 4 + 0];
      float w1 = Wt[kc * 32 + kk][ty * 4 + 1];
      float w2 = Wt[kc * 32 + kk][ty * 4 + 2];
      float w3 = Wt[kc * 32 + kk][ty * 4 + 3];
      acc[0][0] += w0 * xv.x; acc[0][1] += w0 * xv.y; acc[0][2] += w0 * xv.z; acc[0][3] += w0 * xv.w;
      acc[1][0] += w1 * xv.x; acc[1][1] += w1 * xv.y; acc[1][2] += w1 * xv.z; acc[1][3] += w1 * xv.w;
      acc[2][0] += w2 * xv.x; acc[2][1] += w2 * xv.y; acc[2][2] += w2 * xv.z; acc[2][3] += w2 * xv.w;
      acc[3][0] += w3 * xv.x; acc[3][1] += w3 * xv.y; acc[3][2] += w3 * xv.z; acc[3][3] += w3 * xv.w;
    }
  }
#pragma unroll
  for (int j = 0; j < 4; j++) {
    int o = ty * 4 + j;
    float bias = (o < 32) ? bf_[o] : bg_[o - 32];
#pragma unroll
    for (int vi = 0; vi < 4; vi++) tb[tx * 4 + vi][o] = acc[j][vi] + bias;
  }
  __syncthreads();
  int part = t & 3;
  {
    u32 ph[4], plo[4];
#pragma unroll
    for (int e = 0; e < 4; e++) {
      float v0 = tb[n][part * 8 + 2 * e + 0];
      float v1 = tb[n][part * 8 + 2 * e + 1];
      u16 h0 = f2bf(v0), h1 = f2bf(v1);
      u16 l0 = f2bf(v0 - bf2f(h0)), l1 = f2bf(v1 - bf2f(h1));
      ph[e] = (u32)h0 | ((u32)h1 << 16);
      plo[e] = (u32)l0 | ((u32)l1 << 16);
    }
    int jt_g = (n0 >> 4) + (n >> 4), r = n & 15;
    u16* dst = fP + ((size_t)(b * 256) + jt_g) * 1024 + r * 32 + part * 8;
    *(uint4*)dst = make_uint4(ph[0], ph[1], ph[2], ph[3]);
    *(uint4*)(dst + 512) = make_uint4(plo[0], plo[1], plo[2], plo[3]);
  }
  {
    u32 ph[4], plo[4];
#pragma unroll
    for (int e = 0; e < 4; e++) {
      float v0 = tb[n][32 + part * 8 + 2 * e + 0];
      float v1 = tb[n][32 + part * 8 + 2 * e + 1];
      u16 h0 = f2bf(v0), h1 = f2bf(v1);
      u16 l0 = f2bf(v0 - bf2f(h0)), l1 = f2bf(v1 - bf2f(h1));
      ph[e] = (u32)h0 | ((u32)h1 << 16);
      plo[e] = (u32)l0 | ((u32)l1 << 16);
    }
    u16* dst = gT + ((size_t)(b * NPIX) + n0 + n) * 64 + part * 8;
    *(uint4*)dst = make_uint4(ph[0], ph[1], ph[2], ph[3]);
    *(uint4*)(dst + 32) = make_uint4(plo[0], plo[1], plo[2], plo[3]);
  }
}

// ---------------- K4: h projection -> h2[b][j>>5][c][j&31] bf16 ----------------
__global__ __launch_bounds__(256) void k_h(const u16* __restrict__ xT,
                                           const float* __restrict__ Wh,
                                           const float* __restrict__ bh,
                                           u16* __restrict__ h2) {
  __shared__ u16 At[128 * 32];
  __shared__ u16 Bt[128 * 32];
  int blk = blockIdx.x;
  int b = blk >> 6, r = blk & 63;
  int nt = r >> 1, ot = r & 1;
  int n0 = nt * 128, o0 = ot * 128;
  int t = threadIdx.x, lane = t & 63, w = t >> 6;
  int wr = w >> 1, wc = w & 1;
  int coll = lane & 15, cg = lane >> 4;
  f32x4 acc[4][4] = {};
  for (int kc = 0; kc < 8; kc++) {
    __syncthreads();
#pragma unroll
    for (int r2 = 0; r2 < 2; r2++) {
      int s = r2 * 256 + t;
      int row = s >> 2, slot = s & 3;
      int sw = (row ^ (row >> 2)) & 3;
      uint4 va = *(const uint4*)(xT + ((size_t)(b * NPIX + n0 + row)) * NC + kc * 32 + slot * 8);
      *(uint4*)((char*)At + row * 64 + ((slot ^ sw) * 16)) = va;
      const float* wsrc = Wh + (size_t)(o0 + row) * NC + kc * 32 + slot * 8;
      float4 w0 = *(const float4*)wsrc;
      float4 w1 = *(const float4*)(wsrc + 4);
      uint4 vb = make_uint4(cvtpk(w0.x, w0.y), cvtpk(w0.z, w0.w),
                            cvtpk(w1.x, w1.y), cvtpk(w1.z, w1.w));
      *(uint4*)((char*)Bt + row * 64 + ((slot ^ sw) * 16)) = vb;
    }
    __syncthreads();
    bfv8 af[4], bfr[4];
#pragma unroll
    for (int mi = 0; mi < 4; mi++) {
      int row = wr * 64 + mi * 16 + coll;
      int slot = cg ^ ((row ^ (row >> 2)) & 3);
      af[mi] = *(const bfv8*)((const char*)At + row * 64 + slot * 16);
    }
#pragma unroll
    for (int ni = 0; ni < 4; ni++) {
      int row = wc * 64 + ni * 16 + coll;
      int slot = cg ^ ((row ^ (row >> 2)) & 3);
      bfr[ni] = *(const bfv8*)((const char*)Bt + row * 64 + slot * 16);
    }
#pragma unroll
    for (int mi = 0; mi < 4; mi++)
#pragma unroll
      for (int ni = 0; ni < 4; ni++)
        acc[mi][ni] = __builtin_amdgcn_mfma_f32_16x16x32_bf16(af[mi], bfr[ni], acc[mi][ni], 0, 0, 0);
  }
#pragma unroll
  for (int ni = 0; ni < 4; ni++) {
    int o = o0 + wc * 64 + ni * 16 + coll;
    float bias = bh[o];
#pragma unroll
    for (int mi = 0; mi < 4; mi++) {
      int px = n0 + wr * 64 + mi * 16 + cg * 4;
      u32 lo = cvtpk(acc[mi][ni][0] + bias, acc[mi][ni][1] + bias);
      u32 hi = cvtpk(acc[mi][ni][2] + bias, acc[mi][ni][3] + bias);
      *(uint2*)(h2 + (((size_t)(b * 128) + (px >> 5)) * NC + o) * 32 + (px & 31)) =
          make_uint2(lo, hi);
    }
  }
}

// ---------------- K5: pass 1 partials ----------------
__global__ __launch_bounds__(256) void k_pass1(const u16* __restrict__ fP,
                                               const u16* __restrict__ gT,
                                               float2* __restrict__ pmd) {
  __shared__ u16 gs[64 * 64];
  int blk = blockIdx.x;
  int iq = blk & 7, jt = (blk >> 3) & 63, b = blk >> 9;
  int j0 = jt * 64, ibase = iq * 512;
  int t = threadIdx.x, lane = t & 63, w = t >> 6;
  int coll = lane & 15, cg = lane >> 4;
  const u16* fr = fP + ((size_t)(b * 256) + (j0 >> 4) + w) * 1024 + coll * 32 + cg * 8;
  bfv8 ah = *(const bfv8*)fr;
  bfv8 al = *(const bfv8*)(fr + 512);
  float m[4] = {-3e38f, -3e38f, -3e38f, -3e38f}, d[4] = {0.f, 0.f, 0.f, 0.f};
  int r0 = t >> 3, s0 = t & 7;
  uint4 v0 = *(const uint4*)(gT + ((size_t)(b * NPIX) + ibase + r0) * 64 + s0 * 8);
  uint4 v1 = *(const uint4*)(gT + ((size_t)(b * NPIX) + ibase + 32 + r0) * 64 + s0 * 8);
  for (int it2 = 0; it2 < 8; ++it2) {
    __syncthreads();
    *(uint4*)(&gs[r0 * 64 + ((s0 ^ (r0 & 7)) << 3)]) = v0;
    *(uint4*)(&gs[(32 + r0) * 64 + ((s0 ^ (r0 & 7)) << 3)]) = v1;
    __syncthreads();
    if (it2 < 7) {
      v0 = *(const uint4*)(gT + ((size_t)(b * NPIX) + ibase + (it2 + 1) * 64 + r0) * 64 + s0 * 8);
      v1 = *(const uint4*)(gT + ((size_t)(b * NPIX) + ibase + (it2 + 1) * 64 + 32 + r0) * 64 + s0 * 8);
    }
    float sv[4][4];
#pragma unroll
    for (int t4 = 0; t4 < 4; ++t4) {
      int row = t4 * 16 + coll;
      const u16* base = &gs[row * 64];
      bfv8 bh = *(const bfv8*)(base + ((cg ^ (row & 7)) << 3));
      bfv8 bl = *(const bfv8*)(base + (((4 + cg) ^ (row & 7)) << 3));
      f32x4 s = {0.f, 0.f, 0.f, 0.f};
      s = __builtin_amdgcn_mfma_f32_16x16x32_bf16(al, bh, s, 0, 0, 0);
      s = __builtin_amdgcn_mfma_f32_16x16x32_bf16(ah, bl, s, 0, 0, 0);
      s = __builtin_amdgcn_mfma_f32_16x16x32_bf16(ah, bh, s, 0, 0, 0);
      sv[t4][0] = s[0]; sv[t4][1] = s[1]; sv[t4][2] = s[2]; sv[t4][3] = s[3];
    }
#pragma unroll
    for (int r = 0; r < 4; ++r) {
      float ms = fmaxf(fmaxf(sv[0][r], sv[1][r]), fmaxf(sv[2][r], sv[3][r]));
      float nm = fmaxf(m[r], ms);
      d[r] = d[r] * __expf(m[r] - nm) + __expf(sv[0][r] - nm) + __expf(sv[1][r] - nm) +
             __expf(sv[2][r] - nm) + __expf(sv[3][r] - nm);
      m[r] = nm;
    }
  }
#pragma unroll
  for (int r = 0; r < 4; ++r) {
#pragma unroll
    for (int off = 1; off < 16; off <<= 1) {
      float m2 = __shfl_xor(m[r], off);
      float d2 = __shfl_xor(d[r], off);
      float nm = fmaxf(m[r], m2);
      d[r] = d[r] * __expf(m[r] - nm) + d2 * __expf(m2 - nm);
      m[r] = nm;
    }
  }
  if (coll == 0) {
#pragma unroll
    for (int r = 0; r < 4; ++r) {
      int j = j0 + w * 16 + cg * 4 + r;
      pmd[((size_t)(b * 8 + iq)) * NPIX + j] = make_float2(m[r], d[r]);
    }
  }
}

// ---------------- K5b: combine partials -> a_j = M*log2e + log2(D) ----------------
__global__ __launch_bounds__(256) void k_comb(const float2* __restrict__ pmd,
                                              float* __restrict__ aout) {
  int idx = blockIdx.x * 256 + threadIdx.x;  // 16384
  int b = idx >> 12, j = idx & 4095;
  float2 p[8];
  float M = -3e38f;
#pragma unroll
  for (int q = 0; q < 8; ++q) {
    p[q] = pmd[((size_t)(b * 8 + q)) * NPIX + j];
    M = fmaxf(M, p[q].x);
  }
  float D = 0.f;
#pragma unroll
  for (int q = 0; q < 8; ++q) D += p[q].y * __expf(p[q].x - M);
  aout[idx] = fmaf(M, LOG2E, __log2f(D));
}

// ---------------- K6: pass 2 — i-tile 64, 512 thr, full j, fused residual ----------------
// QK: wave (jt_w = w&3, ihalf = w>>2) computes S-tiles (jt_w, isub = ihalf*2+q), g resident.
// PV: wave owns c-slice [w*32, w*32+32) x i 64. Epilogue: out = gamma*O + x.
__global__ __launch_bounds__(512, 2) void k_pass2(const u16* __restrict__ fP,
                                                  const u16* __restrict__ gT,
                                                  const u16* __restrict__ h2,
                                                  const float* __restrict__ arow,
                                                  const float* __restrict__ x,
                                                  const float* __restrict__ gamma,
                                                  float* __restrict__ out) {
  // pl: 2 phases x [4 isub][16 i][64 j] bf16 = 16KB at [0,16384); alds 2x64 f32 at 16384
  // epilogue alias: per-wave 16x36 f32 at w*2304 (18432 total)
  __shared__ char smem[18944];
  int blk = blockIdx.x;
  int it = blk & 63, b = blk >> 6;
  int i0 = it * 64;
  int t = threadIdx.x, lane = t & 63, w = t >> 6;
  int coll = lane & 15, cg = lane >> 4;
  int jt_w = w & 3, ihalf = w >> 2;
  int cbase = w * 32;
  int swz = (coll & 7) << 4;
  float* alds = (float*)(smem + 16384);
  // g B-frags: 2 isub tiles, resident for the whole kernel
  bfv8 gah[2], gal[2];
#pragma unroll
  for (int q = 0; q < 2; ++q) {
    const u16* gr = gT + ((size_t)(b * NPIX) + i0 + (ihalf * 2 + q) * 16 + coll) * 64 + cg * 8;
    gah[q] = *(const bfv8*)gr;
    gal[q] = *(const bfv8*)(gr + 32);
  }
  f32x4 acc[2][4] = {};  // [ct (c 16-sub)][ni (i 16-sub of 64)]
  // h A-frags: c-slice 32 x j-chunk 64, contiguous 1024B wave loads
  const u16* h2b = h2 + ((size_t)(b * 128) * NC + cbase + coll) * 32 + cg * 8;
  bfv8 hv[2][2];
#pragma unroll
  for (int ct = 0; ct < 2; ++ct)
#pragma unroll
    for (int kb = 0; kb < 2; ++kb)
      hv[ct][kb] = *(const bfv8*)(h2b + (size_t)kb * 8192 + ct * 512);
  // f A-frags: this wave's single j-subtile per chunk
  const u16* fPb = fP + ((size_t)(b * 256)) * 1024 + coll * 32 + cg * 8;
  bfv8 fh = *(const bfv8*)(fPb + jt_w * 1024);
  bfv8 fl = *(const bfv8*)(fPb + jt_w * 1024 + 512);
  float apre = 0.f;
  if (t < 64) alds[t] = arow[b * NPIX + t];
  // QK(0): 2 S-tiles
  f32x4 s[2];
#pragma unroll
  for (int q = 0; q < 2; ++q) {
    f32x4 ss = {0.f, 0.f, 0.f, 0.f};
    ss = __builtin_amdgcn_mfma_f32_16x16x32_bf16(fl, gah[q], ss, 0, 0, 0);
    ss = __builtin_amdgcn_mfma_f32_16x16x32_bf16(fh, gal[q], ss, 0, 0, 0);
    ss = __builtin_amdgcn_mfma_f32_16x16x32_bf16(fh, gah[q], ss, 0, 0, 0);
    s[q] = ss;
  }
  // f(1), a(1)
  fh = *(const bfv8*)(fPb + (4 + jt_w) * 1024);
  fl = *(const bfv8*)(fPb + (4 + jt_w) * 1024 + 512);
  if (t < 64) apre = arow[b * NPIX + 64 + t];
  __syncthreads();

  for (int jc = 0; jc < 64; ++jc) {
    int p = jc & 1;
    // ---- exp + P write (2 tiles share the same j-rows -> one av) ----
    {
      int jr = jt_w * 16 + cg * 4;
      float4 av = *(const float4*)&alds[p * 64 + jr];
#pragma unroll
      for (int q = 0; q < 2; ++q) {
        float p0 = exp2f(fmaf(s[q][0], LOG2E, -av.x));
        float p1 = exp2f(fmaf(s[q][1], LOG2E, -av.y));
        float p2 = exp2f(fmaf(s[q][2], LOG2E, -av.z));
        float p3 = exp2f(fmaf(s[q][3], LOG2E, -av.w));
        char* pb = smem + p * 8192 + (ihalf * 2 + q) * 2048 + coll * 128;
        *(uint2*)(pb + ((jt_w * 32 + cg * 8) ^ swz)) =
            make_uint2(cvtpk(p0, p1), cvtpk(p2, p3));
      }
    }
    if (t < 64) alds[((jc + 1) & 1) * 64 + t] = apre;
    __syncthreads();
    // ---- PV: c-slice 32 x i 64 ----
#pragma unroll
    for (int ni = 0; ni < 4; ++ni) {
      const char* pbr = smem + p * 8192 + ni * 2048 + coll * 128;
      bfv8 pa0 = *(const bfv8*)(pbr + ((cg * 16) ^ swz));
      bfv8 pa1 = *(const bfv8*)(pbr + ((64 + cg * 16) ^ swz));
#pragma unroll
      for (int ct = 0; ct < 2; ++ct) {
        acc[ct][ni] = __builtin_amdgcn_mfma_f32_16x16x32_bf16(hv[ct][0], pa0, acc[ct][ni], 0, 0, 0);
        acc[ct][ni] = __builtin_amdgcn_mfma_f32_16x16x32_bf16(hv[ct][1], pa1, acc[ct][ni], 0, 0, 0);
      }
    }
    if (jc < 63) {
      // next h frags
#pragma unroll
      for (int ct = 0; ct < 2; ++ct)
#pragma unroll
        for (int kb = 0; kb < 2; ++kb)
          hv[ct][kb] = *(const bfv8*)(h2b + (size_t)((jc + 1) * 2 + kb) * 8192 + ct * 512);
      // QK(jc+1) with resident g
#pragma unroll
      for (int q = 0; q < 2; ++q) {
        f32x4 ss = {0.f, 0.f, 0.f, 0.f};
        ss = __builtin_amdgcn_mfma_f32_16x16x32_bf16(fl, gah[q], ss, 0, 0, 0);
        ss = __builtin_amdgcn_mfma_f32_16x16x32_bf16(fh, gal[q], ss, 0, 0, 0);
        ss = __builtin_amdgcn_mfma_f32_16x16x32_bf16(fh, gah[q], ss, 0, 0, 0);
        s[q] = ss;
      }
      if (jc < 62) {
        fh = *(const bfv8*)(fPb + (size_t)((jc + 2) * 4 + jt_w) * 1024);
        fl = *(const bfv8*)(fPb + (size_t)((jc + 2) * 4 + jt_w) * 1024 + 512);
        if (t < 64) apre = arow[b * NPIX + (jc + 2) * 64 + t];
      }
    }
  }
  // ---- epilogue: per-wave transpose via LDS, fuse gamma*O + x -> out ----
  float gam = gamma[0];
  int row = lane >> 2, part = lane & 3;
#pragma unroll
  for (int rd = 0; rd < 4; ++rd) {
    int ct = rd >> 1, ih = rd & 1;
    __syncthreads();
    float* tbf = (float*)(smem + w * 2304);
#pragma unroll
    for (int nq = 0; nq < 2; ++nq)
#pragma unroll
      for (int r = 0; r < 4; ++r)
        tbf[(cg * 4 + r) * 36 + nq * 16 + coll] = acc[ct][ih * 2 + nq][r];
    __syncthreads();
    const float* src = tbf + row * 36 + part * 8;
    size_t off = ((size_t)(b * NC) + cbase + ct * 16 + row) * NPIX + i0 + ih * 32 + part * 8;
    float4 x0 = *(const float4*)(x + off);
    float4 x1 = *(const float4*)(x + off + 4);
    float4 o0, o1;
    o0.x = fmaf(gam, src[0], x0.x); o0.y = fmaf(gam, src[1], x0.y);
    o0.z = fmaf(gam, src[2], x0.z); o0.w = fmaf(gam, src[3], x0.w);
    o1.x = fmaf(gam, src[4], x1.x); o1.y = fmaf(gam, src[5], x1.y);
    o1.z = fmaf(gam, src[6], x1.z); o1.w = fmaf(gam, src[7], x1.w);
    *(float4*)(out + off) = o0;
    *(float4*)(out + off + 4) = o1;
  }
}

extern "C" void kernel_launch(void* const* d_in, const int* in_sizes, int n_in,
                              void* d_out, int out_size, void* d_ws, size_t ws_size,
                              hipStream_t stream) {
  (void)in_sizes; (void)n_in; (void)out_size; (void)ws_size;
  const float* x = (const float*)d_in[0];
  const float* Wf = (const float*)d_in[1];
  const float* bf_ = (const float*)d_in[2];
  const float* Wg = (const float*)d_in[3];
  const float* bg_ = (const float*)d_in[4];
  const float* Wh = (const float*)d_in[5];
  const float* bh = (const float*)d_in[6];
  const float* gamma = (const float*)d_in[7];
  float* out = (float*)d_out;
  char* ws = (char*)d_ws;
  const size_t M1 = 1u << 20;
  u16* xT = (u16*)ws;                                  // 8MB
  u16* h2 = (u16*)(ws + 9 * M1);                       // 8MB
  u16* fP = (u16*)(ws + 17 * M1);                      // 2MB
  u16* gT = (u16*)(ws + 19 * M1);                      // 2MB
  float* aout = (float*)(ws + 21 * M1);                // 64KB
  float2* pmd = (float2*)(ws + 21 * M1 + (1u << 17));  // 1MB

  k_fg<<<256, 256, 0, stream>>>(x, Wf, bf_, Wg, bg_, fP, gT, xT);
  k_pass1<<<2048, 256, 0, stream>>>(fP, gT, pmd);
  k_h<<<256, 256, 0, stream>>>(xT, Wh, bh, h2);
  k_comb<<<64, 256, 0, stream>>>(pmd, aout);
  k_pass2<<<256, 512, 0, stream>>>(fP, gT, h2, aout, x, gamma, out);
}

// Round 15
// 117.881 us; speedup vs baseline: 1.0948x; 1.0010x over previous
//
#include <hip/hip_runtime.h>

#define NB 4
#define NC 256
#define NCK 32
#define NPIX 4096

typedef unsigned short u16;
typedef unsigned int u32;
typedef __bf16 bfv8 __attribute__((ext_vector_type(8)));
typedef float f32x4 __attribute__((ext_vector_type(4)));
#define LOG2E 1.4426950408889634f

__device__ inline u16 f2bf(float f) {
  union { float f; u32 u; } v; v.f = f;
  u32 r = v.u + 0x7fffu + ((v.u >> 16) & 1u);  // RNE
  return (u16)(r >> 16);
}
__device__ inline float bf2f(u16 h) {
  union { u32 u; float f; } v; v.u = (u32)h << 16; return v.f;
}
__device__ inline u32 cvtpk(float a, float b) {
  u32 r;
  asm("v_cvt_pk_bf16_f32 %0, %1, %2" : "=v"(r) : "v"(a), "v"(b));
  return r;
}

// ---------------- K3: f,g projections + xT emit ----------------
__global__ __launch_bounds__(256) void k_fg(const float* __restrict__ x,
                                            const float* __restrict__ Wf,
                                            const float* __restrict__ bf_,
                                            const float* __restrict__ Wg,
                                            const float* __restrict__ bg_,
                                            u16* __restrict__ fP,
                                            u16* __restrict__ gT,
                                            u16* __restrict__ xT) {
  __shared__ float Wt[256][65];
  __shared__ float xl[32][68];
  __shared__ float tb[64][68];
  int blk = blockIdx.x;
  int b = blk >> 6;
  int n0 = (blk & 63) * 64;
  int t = threadIdx.x;
  int tx = t & 15, ty = t >> 4;
  for (int r = 0; r < 64; r++) {
    float w = (r < 32) ? Wf[r * 256 + t] : Wg[(r - 32) * 256 + t];
    Wt[t][r] = w;
  }
  float acc[4][4] = {};
  int n = t >> 2, cp = t & 3;
  for (int kc = 0; kc < 8; kc++) {
    __syncthreads();
#pragma unroll
    for (int r = 0; r < 2; r++) {
      int e = (r * 256 + t) * 4;
      int row = e >> 6, col = e & 63;
      *(float4*)&xl[row][col] =
          *(const float4*)(x + ((size_t)(b * NC + kc * 32 + row)) * NPIX + n0 + col);
    }
    __syncthreads();
    {
      u32 uu[4];
#pragma unroll
      for (int q = 0; q < 4; q++)
        uu[q] = cvtpk(xl[cp * 8 + 2 * q][n], xl[cp * 8 + 2 * q + 1][n]);
      *(uint4*)(xT + ((size_t)(b * NPIX) + n0 + n) * NC + kc * 32 + cp * 8) =
          make_uint4(uu[0], uu[1], uu[2], uu[3]);
    }
#pragma unroll
    for (int kk = 0; kk < 32; kk++) {
      float4 xv = *(const float4*)&xl[kk][tx * 4];
      float w0 = Wt[kc * 32 + kk][ty * 4 + 0];
      float w1 = Wt[kc * 32 + kk][ty * 4 + 1];
      float w2 = Wt[kc * 32 + kk][ty * 4 + 2];
      float w3 = Wt[kc * 32 + kk][ty * 4 + 3];
      acc[0][0] += w0 * xv.x; acc[0][1] += w0 * xv.y; acc[0][2] += w0 * xv.z; acc[0][3] += w0 * xv.w;
      acc[1][0] += w1 * xv.x; acc[1][1] += w1 * xv.y; acc[1][2] += w1 * xv.z; acc[1][3] += w1 * xv.w;
      acc[2][0] += w2 * xv.x; acc[2][1] += w2 * xv.y; acc[2][2] += w2 * xv.z; acc[2][3] += w2 * xv.w;
      acc[3][0] += w3 * xv.x; acc[3][1] += w3 * xv.y; acc[3][2] += w3 * xv.z; acc[3][3] += w3 * xv.w;
    }
  }
#pragma unroll
  for (int j = 0; j < 4; j++) {
    int o = ty * 4 + j;
    float bias = (o < 32) ? bf_[o] : bg_[o - 32];
#pragma unroll
    for (int vi = 0; vi < 4; vi++) tb[tx * 4 + vi][o] = acc[j][vi] + bias;
  }
  __syncthreads();
  int part = t & 3;
  {
    u32 ph[4], plo[4];
#pragma unroll
    for (int e = 0; e < 4; e++) {
      float v0 = tb[n][part * 8 + 2 * e + 0];
      float v1 = tb[n][part * 8 + 2 * e + 1];
      u16 h0 = f2bf(v0), h1 = f2bf(v1);
      u16 l0 = f2bf(v0 - bf2f(h0)), l1 = f2bf(v1 - bf2f(h1));
      ph[e] = (u32)h0 | ((u32)h1 << 16);
      plo[e] = (u32)l0 | ((u32)l1 << 16);
    }
    int jt_g = (n0 >> 4) + (n >> 4), r = n & 15;
    u16* dst = fP + ((size_t)(b * 256) + jt_g) * 1024 + r * 32 + part * 8;
    *(uint4*)dst = make_uint4(ph[0], ph[1], ph[2], ph[3]);
    *(uint4*)(dst + 512) = make_uint4(plo[0], plo[1], plo[2], plo[3]);
  }
  {
    u32 ph[4], plo[4];
#pragma unroll
    for (int e = 0; e < 4; e++) {
      float v0 = tb[n][32 + part * 8 + 2 * e + 0];
      float v1 = tb[n][32 + part * 8 + 2 * e + 1];
      u16 h0 = f2bf(v0), h1 = f2bf(v1);
      u16 l0 = f2bf(v0 - bf2f(h0)), l1 = f2bf(v1 - bf2f(h1));
      ph[e] = (u32)h0 | ((u32)h1 << 16);
      plo[e] = (u32)l0 | ((u32)l1 << 16);
    }
    u16* dst = gT + ((size_t)(b * NPIX) + n0 + n) * 64 + part * 8;
    *(uint4*)dst = make_uint4(ph[0], ph[1], ph[2], ph[3]);
    *(uint4*)(dst + 32) = make_uint4(plo[0], plo[1], plo[2], plo[3]);
  }
}

// ---------------- K4: h projection -> h2[b][j>>5][c][j&31] bf16 ----------------
__global__ __launch_bounds__(256) void k_h(const u16* __restrict__ xT,
                                           const float* __restrict__ Wh,
                                           const float* __restrict__ bh,
                                           u16* __restrict__ h2) {
  __shared__ u16 At[128 * 32];
  __shared__ u16 Bt[128 * 32];
  int blk = blockIdx.x;
  int b = blk >> 6, r = blk & 63;
  int nt = r >> 1, ot = r & 1;
  int n0 = nt * 128, o0 = ot * 128;
  int t = threadIdx.x, lane = t & 63, w = t >> 6;
  int wr = w >> 1, wc = w & 1;
  int coll = lane & 15, cg = lane >> 4;
  f32x4 acc[4][4] = {};
  for (int kc = 0; kc < 8; kc++) {
    __syncthreads();
#pragma unroll
    for (int r2 = 0; r2 < 2; r2++) {
      int s = r2 * 256 + t;
      int row = s >> 2, slot = s & 3;
      int sw = (row ^ (row >> 2)) & 3;
      uint4 va = *(const uint4*)(xT + ((size_t)(b * NPIX + n0 + row)) * NC + kc * 32 + slot * 8);
      *(uint4*)((char*)At + row * 64 + ((slot ^ sw) * 16)) = va;
      const float* wsrc = Wh + (size_t)(o0 + row) * NC + kc * 32 + slot * 8;
      float4 w0 = *(const float4*)wsrc;
      float4 w1 = *(const float4*)(wsrc + 4);
      uint4 vb = make_uint4(cvtpk(w0.x, w0.y), cvtpk(w0.z, w0.w),
                            cvtpk(w1.x, w1.y), cvtpk(w1.z, w1.w));
      *(uint4*)((char*)Bt + row * 64 + ((slot ^ sw) * 16)) = vb;
    }
    __syncthreads();
    bfv8 af[4], bfr[4];
#pragma unroll
    for (int mi = 0; mi < 4; mi++) {
      int row = wr * 64 + mi * 16 + coll;
      int slot = cg ^ ((row ^ (row >> 2)) & 3);
      af[mi] = *(const bfv8*)((const char*)At + row * 64 + slot * 16);
    }
#pragma unroll
    for (int ni = 0; ni < 4; ni++) {
      int row = wc * 64 + ni * 16 + coll;
      int slot = cg ^ ((row ^ (row >> 2)) & 3);
      bfr[ni] = *(const bfv8*)((const char*)Bt + row * 64 + slot * 16);
    }
#pragma unroll
    for (int mi = 0; mi < 4; mi++)
#pragma unroll
      for (int ni = 0; ni < 4; ni++)
        acc[mi][ni] = __builtin_amdgcn_mfma_f32_16x16x32_bf16(af[mi], bfr[ni], acc[mi][ni], 0, 0, 0);
  }
#pragma unroll
  for (int ni = 0; ni < 4; ni++) {
    int o = o0 + wc * 64 + ni * 16 + coll;
    float bias = bh[o];
#pragma unroll
    for (int mi = 0; mi < 4; mi++) {
      int px = n0 + wr * 64 + mi * 16 + cg * 4;
      u32 lo = cvtpk(acc[mi][ni][0] + bias, acc[mi][ni][1] + bias);
      u32 hi = cvtpk(acc[mi][ni][2] + bias, acc[mi][ni][3] + bias);
      *(uint2*)(h2 + (((size_t)(b * 128) + (px >> 5)) * NC + o) * 32 + (px & 31)) =
          make_uint2(lo, hi);
    }
  }
}

// ---------------- K5: pass 1 partials ----------------
__global__ __launch_bounds__(256) void k_pass1(const u16* __restrict__ fP,
                                               const u16* __restrict__ gT,
                                               float2* __restrict__ pmd) {
  __shared__ u16 gs[64 * 64];
  int blk = blockIdx.x;
  int iq = blk & 7, jt = (blk >> 3) & 63, b = blk >> 9;
  int j0 = jt * 64, ibase = iq * 512;
  int t = threadIdx.x, lane = t & 63, w = t >> 6;
  int coll = lane & 15, cg = lane >> 4;
  const u16* fr = fP + ((size_t)(b * 256) + (j0 >> 4) + w) * 1024 + coll * 32 + cg * 8;
  bfv8 ah = *(const bfv8*)fr;
  bfv8 al = *(const bfv8*)(fr + 512);
  float m[4] = {-3e38f, -3e38f, -3e38f, -3e38f}, d[4] = {0.f, 0.f, 0.f, 0.f};
  int r0 = t >> 3, s0 = t & 7;
  uint4 v0 = *(const uint4*)(gT + ((size_t)(b * NPIX) + ibase + r0) * 64 + s0 * 8);
  uint4 v1 = *(const uint4*)(gT + ((size_t)(b * NPIX) + ibase + 32 + r0) * 64 + s0 * 8);
  for (int it2 = 0; it2 < 8; ++it2) {
    __syncthreads();
    *(uint4*)(&gs[r0 * 64 + ((s0 ^ (r0 & 7)) << 3)]) = v0;
    *(uint4*)(&gs[(32 + r0) * 64 + ((s0 ^ (r0 & 7)) << 3)]) = v1;
    __syncthreads();
    if (it2 < 7) {
      v0 = *(const uint4*)(gT + ((size_t)(b * NPIX) + ibase + (it2 + 1) * 64 + r0) * 64 + s0 * 8);
      v1 = *(const uint4*)(gT + ((size_t)(b * NPIX) + ibase + (it2 + 1) * 64 + 32 + r0) * 64 + s0 * 8);
    }
    float sv[4][4];
#pragma unroll
    for (int t4 = 0; t4 < 4; ++t4) {
      int row = t4 * 16 + coll;
      const u16* base = &gs[row * 64];
      bfv8 bh = *(const bfv8*)(base + ((cg ^ (row & 7)) << 3));
      bfv8 bl = *(const bfv8*)(base + (((4 + cg) ^ (row & 7)) << 3));
      f32x4 s = {0.f, 0.f, 0.f, 0.f};
      s = __builtin_amdgcn_mfma_f32_16x16x32_bf16(al, bh, s, 0, 0, 0);
      s = __builtin_amdgcn_mfma_f32_16x16x32_bf16(ah, bl, s, 0, 0, 0);
      s = __builtin_amdgcn_mfma_f32_16x16x32_bf16(ah, bh, s, 0, 0, 0);
      sv[t4][0] = s[0]; sv[t4][1] = s[1]; sv[t4][2] = s[2]; sv[t4][3] = s[3];
    }
#pragma unroll
    for (int r = 0; r < 4; ++r) {
      float ms = fmaxf(fmaxf(sv[0][r], sv[1][r]), fmaxf(sv[2][r], sv[3][r]));
      float nm = fmaxf(m[r], ms);
      d[r] = d[r] * __expf(m[r] - nm) + __expf(sv[0][r] - nm) + __expf(sv[1][r] - nm) +
             __expf(sv[2][r] - nm) + __expf(sv[3][r] - nm);
      m[r] = nm;
    }
  }
#pragma unroll
  for (int r = 0; r < 4; ++r) {
#pragma unroll
    for (int off = 1; off < 16; off <<= 1) {
      float m2 = __shfl_xor(m[r], off);
      float d2 = __shfl_xor(d[r], off);
      float nm = fmaxf(m[r], m2);
      d[r] = d[r] * __expf(m[r] - nm) + d2 * __expf(m2 - nm);
      m[r] = nm;
    }
  }
  if (coll == 0) {
#pragma unroll
    for (int r = 0; r < 4; ++r) {
      int j = j0 + w * 16 + cg * 4 + r;
      pmd[((size_t)(b * 8 + iq)) * NPIX + j] = make_float2(m[r], d[r]);
    }
  }
}

// ---------------- K5b: combine partials -> a_j = M*log2e + log2(D) ----------------
__global__ __launch_bounds__(256) void k_comb(const float2* __restrict__ pmd,
                                              float* __restrict__ aout) {
  int idx = blockIdx.x * 256 + threadIdx.x;  // 16384
  int b = idx >> 12, j = idx & 4095;
  float2 p[8];
  float M = -3e38f;
#pragma unroll
  for (int q = 0; q < 8; ++q) {
    p[q] = pmd[((size_t)(b * 8 + q)) * NPIX + j];
    M = fmaxf(M, p[q].x);
  }
  float D = 0.f;
#pragma unroll
  for (int q = 0; q < 8; ++q) D += p[q].y * __expf(p[q].x - M);
  aout[idx] = fmaf(M, LOG2E, __log2f(D));
}

// ---------------- K6: pass 2 — i-tile 64, 512 thr, full j, fused residual ----------------
// QK: wave (jt_w = w&3, ihalf = w>>2) computes S-tiles (jt_w, isub = ihalf*2+q), g resident.
// PV: wave owns c-slice [w*32, w*32+32) x i 64. Epilogue: out = gamma*O + x.
__global__ __launch_bounds__(512, 2) void k_pass2(const u16* __restrict__ fP,
                                                  const u16* __restrict__ gT,
                                                  const u16* __restrict__ h2,
                                                  const float* __restrict__ arow,
                                                  const float* __restrict__ x,
                                                  const float* __restrict__ gamma,
                                                  float* __restrict__ out) {
  // pl: 2 phases x [4 isub][16 i][64 j] bf16 = 16KB at [0,16384); alds 2x64 f32 at 16384
  // epilogue alias: per-wave 16x36 f32 at w*2304 (18432 total)
  __shared__ char smem[18944];
  int blk = blockIdx.x;
  int it = blk & 63, b = blk >> 6;
  int i0 = it * 64;
  int t = threadIdx.x, lane = t & 63, w = t >> 6;
  int coll = lane & 15, cg = lane >> 4;
  int jt_w = w & 3, ihalf = w >> 2;
  int cbase = w * 32;
  int swz = (coll & 7) << 4;
  float* alds = (float*)(smem + 16384);
  // g B-frags: 2 isub tiles, resident for the whole kernel
  bfv8 gah[2], gal[2];
#pragma unroll
  for (int q = 0; q < 2; ++q) {
    const u16* gr = gT + ((size_t)(b * NPIX) + i0 + (ihalf * 2 + q) * 16 + coll) * 64 + cg * 8;
    gah[q] = *(const bfv8*)gr;
    gal[q] = *(const bfv8*)(gr + 32);
  }
  f32x4 acc[2][4] = {};  // [ct (c 16-sub)][ni (i 16-sub of 64)]
  // h A-frags: c-slice 32 x j-chunk 64, contiguous 1024B wave loads
  const u16* h2b = h2 + ((size_t)(b * 128) * NC + cbase + coll) * 32 + cg * 8;
  bfv8 hv[2][2];
#pragma unroll
  for (int ct = 0; ct < 2; ++ct)
#pragma unroll
    for (int kb = 0; kb < 2; ++kb)
      hv[ct][kb] = *(const bfv8*)(h2b + (size_t)kb * 8192 + ct * 512);
  // f A-frags: this wave's single j-subtile per chunk
  const u16* fPb = fP + ((size_t)(b * 256)) * 1024 + coll * 32 + cg * 8;
  bfv8 fh = *(const bfv8*)(fPb + jt_w * 1024);
  bfv8 fl = *(const bfv8*)(fPb + jt_w * 1024 + 512);
  float apre = 0.f;
  if (t < 64) alds[t] = arow[b * NPIX + t];
  // QK(0): 2 S-tiles
  f32x4 s[2];
#pragma unroll
  for (int q = 0; q < 2; ++q) {
    f32x4 ss = {0.f, 0.f, 0.f, 0.f};
    ss = __builtin_amdgcn_mfma_f32_16x16x32_bf16(fl, gah[q], ss, 0, 0, 0);
    ss = __builtin_amdgcn_mfma_f32_16x16x32_bf16(fh, gal[q], ss, 0, 0, 0);
    ss = __builtin_amdgcn_mfma_f32_16x16x32_bf16(fh, gah[q], ss, 0, 0, 0);
    s[q] = ss;
  }
  // f(1), a(1)
  fh = *(const bfv8*)(fPb + (4 + jt_w) * 1024);
  fl = *(const bfv8*)(fPb + (4 + jt_w) * 1024 + 512);
  if (t < 64) apre = arow[b * NPIX + 64 + t];
  __syncthreads();

  for (int jc = 0; jc < 64; ++jc) {
    int p = jc & 1;
    // ---- exp + P write (2 tiles share the same j-rows -> one av) ----
    {
      int jr = jt_w * 16 + cg * 4;
      float4 av = *(const float4*)&alds[p * 64 + jr];
#pragma unroll
      for (int q = 0; q < 2; ++q) {
        float p0 = exp2f(fmaf(s[q][0], LOG2E, -av.x));
        float p1 = exp2f(fmaf(s[q][1], LOG2E, -av.y));
        float p2 = exp2f(fmaf(s[q][2], LOG2E, -av.z));
        float p3 = exp2f(fmaf(s[q][3], LOG2E, -av.w));
        char* pb = smem + p * 8192 + (ihalf * 2 + q) * 2048 + coll * 128;
        *(uint2*)(pb + ((jt_w * 32 + cg * 8) ^ swz)) =
            make_uint2(cvtpk(p0, p1), cvtpk(p2, p3));
      }
    }
    if (t < 64) alds[((jc + 1) & 1) * 64 + t] = apre;
    __syncthreads();
    // ---- PV: c-slice 32 x i 64 ----
#pragma unroll
    for (int ni = 0; ni < 4; ++ni) {
      const char* pbr = smem + p * 8192 + ni * 2048 + coll * 128;
      bfv8 pa0 = *(const bfv8*)(pbr + ((cg * 16) ^ swz));
      bfv8 pa1 = *(const bfv8*)(pbr + ((64 + cg * 16) ^ swz));
#pragma unroll
      for (int ct = 0; ct < 2; ++ct) {
        acc[ct][ni] = __builtin_amdgcn_mfma_f32_16x16x32_bf16(hv[ct][0], pa0, acc[ct][ni], 0, 0, 0);
        acc[ct][ni] = __builtin_amdgcn_mfma_f32_16x16x32_bf16(hv[ct][1], pa1, acc[ct][ni], 0, 0, 0);
      }
    }
    if (jc < 63) {
      // next h frags
#pragma unroll
      for (int ct = 0; ct < 2; ++ct)
#pragma unroll
        for (int kb = 0; kb < 2; ++kb)
          hv[ct][kb] = *(const bfv8*)(h2b + (size_t)((jc + 1) * 2 + kb) * 8192 + ct * 512);
      // QK(jc+1) with resident g
#pragma unroll
      for (int q = 0; q < 2; ++q) {
        f32x4 ss = {0.f, 0.f, 0.f, 0.f};
        ss = __builtin_amdgcn_mfma_f32_16x16x32_bf16(fl, gah[q], ss, 0, 0, 0);
        ss = __builtin_amdgcn_mfma_f32_16x16x32_bf16(fh, gal[q], ss, 0, 0, 0);
        ss = __builtin_amdgcn_mfma_f32_16x16x32_bf16(fh, gah[q], ss, 0, 0, 0);
        s[q] = ss;
      }
      if (jc < 62) {
        fh = *(const bfv8*)(fPb + (size_t)((jc + 2) * 4 + jt_w) * 1024);
        fl = *(const bfv8*)(fPb + (size_t)((jc + 2) * 4 + jt_w) * 1024 + 512);
        if (t < 64) apre = arow[b * NPIX + (jc + 2) * 64 + t];
      }
    }
  }
  // ---- epilogue: per-wave transpose via LDS, fuse gamma*O + x -> out ----
  float gam = gamma[0];
  int row = lane >> 2, part = lane & 3;
#pragma unroll
  for (int rd = 0; rd < 4; ++rd) {
    int ct = rd >> 1, ih = rd & 1;
    __syncthreads();
    float* tbf = (float*)(smem + w * 2304);
#pragma unroll
    for (int nq = 0; nq < 2; ++nq)
#pragma unroll
      for (int r = 0; r < 4; ++r)
        tbf[(cg * 4 + r) * 36 + nq * 16 + coll] = acc[ct][ih * 2 + nq][r];
    __syncthreads();
    const float* src = tbf + row * 36 + part * 8;
    size_t off = ((size_t)(b * NC) + cbase + ct * 16 + row) * NPIX + i0 + ih * 32 + part * 8;
    float4 x0 = *(const float4*)(x + off);
    float4 x1 = *(const float4*)(x + off + 4);
    float4 o0, o1;
    o0.x = fmaf(gam, src[0], x0.x); o0.y = fmaf(gam, src[1], x0.y);
    o0.z = fmaf(gam, src[2], x0.z); o0.w = fmaf(gam, src[3], x0.w);
    o1.x = fmaf(gam, src[4], x1.x); o1.y = fmaf(gam, src[5], x1.y);
    o1.z = fmaf(gam, src[6], x1.z); o1.w = fmaf(gam, src[7], x1.w);
    *(float4*)(out + off) = o0;
    *(float4*)(out + off + 4) = o1;
  }
}

extern "C" void kernel_launch(void* const* d_in, const int* in_sizes, int n_in,
                              void* d_out, int out_size, void* d_ws, size_t ws_size,
                              hipStream_t stream) {
  (void)in_sizes; (void)n_in; (void)out_size; (void)ws_size;
  const float* x = (const float*)d_in[0];
  const float* Wf = (const float*)d_in[1];
  const float* bf_ = (const float*)d_in[2];
  const float* Wg = (const float*)d_in[3];
  const float* bg_ = (const float*)d_in[4];
  const float* Wh = (const float*)d_in[5];
  const float* bh = (const float*)d_in[6];
  const float* gamma = (const float*)d_in[7];
  float* out = (float*)d_out;
  char* ws = (char*)d_ws;
  const size_t M1 = 1u << 20;
  u16* xT = (u16*)ws;                                  // 8MB
  u16* h2 = (u16*)(ws + 9 * M1);                       // 8MB
  u16* fP = (u16*)(ws + 17 * M1);                      // 2MB
  u16* gT = (u16*)(ws + 19 * M1);                      // 2MB
  float* aout = (float*)(ws + 21 * M1);                // 64KB
  float2* pmd = (float2*)(ws + 21 * M1 + (1u << 17));  // 1MB

  k_fg<<<256, 256, 0, stream>>>(x, Wf, bf_, Wg, bg_, fP, gT, xT);
  k_pass1<<<2048, 256, 0, stream>>>(fP, gT, pmd);
  k_h<<<256, 256, 0, stream>>>(xT, Wh, bh, h2);
  k_comb<<<64, 256, 0, stream>>>(pmd, aout);
  k_pass2<<<256, 512, 0, stream>>>(fP, gT, h2, aout, x, gamma, out);
}